// Round 10
// baseline (346.098 us; speedup 1.0000x reference)
//
#include <hip/hip_runtime.h>
#include <math.h>

#define BATCH 2
#define LSEQ 16384
#define DM 60
#define DI 120
#define NCH 512
#define TCH 32    // LSEQ / NCH
#define HH 128
#define WW 128

typedef __attribute__((ext_vector_type(8))) short bhalf8;
typedef __attribute__((ext_vector_type(4))) short short4v;
typedef __attribute__((ext_vector_type(4))) float f32x4;

__device__ __forceinline__ float sigmoidf_(float x){ return __builtin_amdgcn_rcpf(1.0f + __expf(-x)); }
__device__ __forceinline__ float siluf_(float x){ return x * sigmoidf_(x); }
__device__ __forceinline__ float softplusf_(float x){ return (x > 20.0f) ? x : __logf(1.0f + __expf(x)); }
__device__ __forceinline__ short f2b(float f){   // RNE fp32->bf16 (finite inputs)
  union{float f; unsigned u;} v; v.f = f;
  unsigned r = (v.u + 0x7fffu + ((v.u >> 16) & 1u)) >> 16;
  return (short)r;
}
__device__ __forceinline__ float b2f(short s){
  union{float f; unsigned u;} v; v.u = ((unsigned)(unsigned short)s) << 16; return v.f;
}

__device__ __forceinline__ float waveReduceSum(float v){
  #pragma unroll
  for (int off = 32; off > 0; off >>= 1) v += __shfl_xor(v, off, 64);
  return v;
}

// powers: dA[n] = r^(n+1), log-depth tree
__device__ __forceinline__ void powers16(float r, float* dA){
  dA[0] = r;
  #pragma unroll
  for (int n = 1; n < 16; n++) dA[n] = dA[(n-1)>>1] * dA[n>>1];
}

// =============== weight pre-pack: ipw -> [l][240][64] bf16; xpw -> [l][48][128] bf16 ===============
__global__ __launch_bounds__(256) void k_pack(
    const float* __restrict__ ipw, const float* __restrict__ xpw, short* __restrict__ pk)
{
  int i = blockIdx.x*256 + threadIdx.x;
  if (i < 2*240*64){
    int l = i / (240*64);
    int rem = i % (240*64);
    int n = rem / 64, k = rem % 64;
    float v = (k < 60) ? ipw[(size_t)l*240*60 + n*60 + k] : 0.f;
    pk[i] = f2b(v);
  } else if (i < 30720 + 2*48*128){
    int j = i - 30720;
    int l = j / (48*128);
    int rem = j % (48*128);
    int n = rem / 128, k = rem % 128;
    float v = (n < 36 && k < 120) ? xpw[(size_t)l*36*120 + n*120 + k] : 0.f;
    pk[i] = f2b(v);
  }
}

// ====== fused LN + in_proj(MFMA) + conv1d + x_proj(MFMA) + dt_proj + chunk-scan ======
// 64 rows (2 scan chunks) per block; halo 3. ALL global stores deferred past last barrier.
__global__ __launch_bounds__(256) void k_lnxp(
    const float* __restrict__ srcf, const short* __restrict__ srcb,
    const float* __restrict__ ln_w, const float* __restrict__ ln_b,
    const short* __restrict__ ipB,   // [240][64] bf16
    const float* __restrict__ cw, const float* __restrict__ cb,
    const short* __restrict__ xpB,   // [48][128] bf16
    const float* __restrict__ dtw, const float* __restrict__ dtb,
    const float* __restrict__ A_log,
    short* __restrict__ zs, short* __restrict__ xcg,
    short* __restrict__ delta, short* __restrict__ BCg,
    float* __restrict__ ap, float* __restrict__ he)
{
  __shared__ __align__(16) char smem[64928];
  short* hnB  = (short*)smem;            // [80][72] bf16 (phase 1-2)
  short* xcB  = (short*)smem;            // [64][136] bf16 (phase 3+, aliases hnB)
  short* xinB = (short*)(smem + 17408);  // [80][136] bf16
  short* zsL  = (short*)(smem + 39168);  // [64][120] bf16
  short* BCL  = (short*)(smem + 54528);  // [64][32] bf16
  float* dtsh = (float*)(smem + 58624);  // [64][4]
  float* cwL  = (float*)(smem + 59648);  // [120][4]
  float* cbL  = (float*)(smem + 61568);  // [120]
  float* Wd5  = (float*)(smem + 62048);  // [120][5]
  float* bdL  = (float*)(smem + 64448);  // [120]
  const int tid = threadIdx.x;
  const int wave = tid >> 6, lane = tid & 63;
  const int m = lane & 15, quad = lane >> 4;
  const int row0 = blockIdx.x * 64;
  const int seq0 = (row0 / LSEQ) * LSEQ;
  for (int i = tid; i < 480; i += 256){ cwL[i] = cw[i]; Wd5[(i/4)*5 + (i%4)] = dtw[i]; }
  for (int i = tid; i < 120; i += 256){ cbL[i] = cb[i]; bdL[i] = dtb[i]; }
  // phase 1: LN -> hnB bf16 (rows 0..79; r>=67 or pre-batch -> 0)
  float lw = (lane < 60) ? ln_w[lane] : 0.f;
  float lb = (lane < 60) ? ln_b[lane] : 0.f;
  for (int r = wave; r < 80; r += 4){
    int grow = row0 - 3 + r;
    bool valid = (r < 67) && (grow >= seq0);
    float v = 0.f;
    if (valid && lane < 60)
      v = srcb ? b2f(srcb[(size_t)grow*60 + lane]) : srcf[(size_t)grow*60 + lane];
    float mu = waveReduceSum(v) * (1.0f/60.0f);
    float dv = (valid && lane < 60) ? (v - mu) : 0.f;
    float var = waveReduceSum(dv*dv) * (1.0f/60.0f);
    float rs = rsqrtf(var + 1e-5f);
    float hv = (valid && lane < 60) ? (dv*rs*lw + lb) : 0.f;
    hnB[r*72 + lane] = f2b(hv);
  }
  __syncthreads();
  // phase 2: in_proj MFMA, 5 mtiles x 15 ntiles; zs -> zsL (LDS), xin -> xinB
  for (int t = wave; t < 75; t += 4){
    int mtile = t / 15, ntile = t % 15;
    f32x4 acc = {0.f,0.f,0.f,0.f};
    #pragma unroll
    for (int ks = 0; ks < 2; ks++){
      bhalf8 a = *(const bhalf8*)&hnB[(mtile*16 + m)*72 + ks*32 + quad*8];
      bhalf8 b = *(const bhalf8*)&ipB[(ntile*16 + m)*64 + ks*32 + quad*8];
      acc = __builtin_amdgcn_mfma_f32_16x16x32_bf16(a, b, acc, 0, 0, 0);
    }
    int n = ntile*16 + m;
    #pragma unroll
    for (int reg = 0; reg < 4; reg++){
      int r = mtile*16 + quad*4 + reg;
      float val = acc[reg];
      if (n < 120){
        xinB[r*136 + n] = f2b(val);
      } else if (r >= 3 && r < 67){
        zsL[(r-3)*120 + (n - 120)] = f2b(siluf_(val));
      }
    }
  }
  __syncthreads();
  // phase 3: conv1d(4 taps)+silu -> xcB bf16 (K-pad 120..127 = 0)
  #pragma unroll
  for (int j = 0; j < 30; j++){
    int i = tid + j*256;
    int r = i/120, c = i%120;
    float a = cbL[c];
    #pragma unroll
    for (int k = 0; k < 4; k++)
      a += cwL[c*4+k] * b2f(xinB[(r+k)*136 + c]);
    a = siluf_(a);
    xcB[r*136 + c] = f2b(a);
  }
  for (int i = tid; i < 64*8; i += 256)
    xcB[(i >> 3)*136 + 120 + (i & 7)] = 0;
  __syncthreads();
  // phase 4: x_proj MFMA: wave w -> mtile w; 3 ntiles; K=128; dt->dtsh, B/C->BCL
  {
    f32x4 acc0 = {0.f,0.f,0.f,0.f}, acc1 = {0.f,0.f,0.f,0.f}, acc2 = {0.f,0.f,0.f,0.f};
    #pragma unroll
    for (int ks = 0; ks < 4; ks++){
      bhalf8 a  = *(const bhalf8*)&xcB[(wave*16 + m)*136 + ks*32 + quad*8];
      bhalf8 b0 = *(const bhalf8*)&xpB[(0*16 + m)*128 + ks*32 + quad*8];
      bhalf8 b1 = *(const bhalf8*)&xpB[(1*16 + m)*128 + ks*32 + quad*8];
      bhalf8 b2 = *(const bhalf8*)&xpB[(2*16 + m)*128 + ks*32 + quad*8];
      acc0 = __builtin_amdgcn_mfma_f32_16x16x32_bf16(a, b0, acc0, 0, 0, 0);
      acc1 = __builtin_amdgcn_mfma_f32_16x16x32_bf16(a, b1, acc1, 0, 0, 0);
      acc2 = __builtin_amdgcn_mfma_f32_16x16x32_bf16(a, b2, acc2, 0, 0, 0);
    }
    f32x4 accs[3] = {acc0, acc1, acc2};
    #pragma unroll
    for (int nt = 0; nt < 3; nt++){
      int n = nt*16 + m;
      #pragma unroll
      for (int reg = 0; reg < 4; reg++){
        int r = wave*16 + quad*4 + reg;
        float val = accs[nt][reg];
        if (n < 4)       dtsh[r*4 + n] = val;
        else if (n < 36) BCL[r*32 + (n - 4)] = f2b(val);
      }
    }
  }
  __syncthreads();
  // ---- no more barriers below; all global stores cluster here to kernel end ----
  // phase 5: dt_proj + softplus -> delta global (bf16, coalesced)
  #pragma unroll
  for (int j = 0; j < 30; j++){
    int i = tid + j*256;
    int row = i/120, d = i%120;
    float t0 = dtsh[row*4], t1 = dtsh[row*4+1], t2 = dtsh[row*4+2], t3 = dtsh[row*4+3];
    float a = bdL[d] + t0*Wd5[d*5] + t1*Wd5[d*5+1] + t2*Wd5[d*5+2] + t3*Wd5[d*5+3];
    delta[(size_t)(row0 + row)*120 + d] = f2b(softplusf_(a));
  }
  // phase 6: fused scan pass 1 over this block's two 32-row chunks
  if (tid < 240){
    const int cc = tid / 120, d = tid % 120;
    const int b = row0 / LSEQ;
    const int cglob = ((row0 % LSEQ) >> 5) + cc;
    float A2[16], h[16];
    #pragma unroll
    for (int n = 0; n < 16; n++){ A2[n] = -__expf(A_log[d*16+n]) * 1.44269504f; h[n] = 0.f; }
    bool fastp = true;
    #pragma unroll
    for (int n = 1; n < 16; n++)
      fastp = fastp && (fabsf(A2[n] - (n+1)*A2[0]) <= 1e-4f*fabsf(A2[n]));
    const float w0 = Wd5[d*5], w1 = Wd5[d*5+1], w2 = Wd5[d*5+2], w3 = Wd5[d*5+3];
    const float bd = bdL[d];
    const int rbase = cc*32;
    int base = (cglob*BATCH + b)*(DI*16) + d*16;
    if (fastp){
      float P = 1.f;
      const float A20 = A2[0];
      for (int t = 0; t < 32; t++){
        int row = rbase + t;
        float4 t4 = *(const float4*)&dtsh[row*4];
        float del = softplusf_(bd + t4.x*w0 + t4.y*w1 + t4.z*w2 + t4.w*w3);
        float xcv = b2f(xcB[row*136 + d]);
        float dx = del * xcv;
        float r = exp2f(del * A20);
        P *= r;
        float dA[16]; powers16(r, dA);
        short4v s0 = *(const short4v*)&BCL[row*32+0];
        short4v s1 = *(const short4v*)&BCL[row*32+4];
        short4v s2 = *(const short4v*)&BCL[row*32+8];
        short4v s3 = *(const short4v*)&BCL[row*32+12];
        h[0]=dA[0]*h[0]+dx*b2f(s0.x);  h[1]=dA[1]*h[1]+dx*b2f(s0.y);
        h[2]=dA[2]*h[2]+dx*b2f(s0.z);  h[3]=dA[3]*h[3]+dx*b2f(s0.w);
        h[4]=dA[4]*h[4]+dx*b2f(s1.x);  h[5]=dA[5]*h[5]+dx*b2f(s1.y);
        h[6]=dA[6]*h[6]+dx*b2f(s1.z);  h[7]=dA[7]*h[7]+dx*b2f(s1.w);
        h[8]=dA[8]*h[8]+dx*b2f(s2.x);  h[9]=dA[9]*h[9]+dx*b2f(s2.y);
        h[10]=dA[10]*h[10]+dx*b2f(s2.z); h[11]=dA[11]*h[11]+dx*b2f(s2.w);
        h[12]=dA[12]*h[12]+dx*b2f(s3.x); h[13]=dA[13]*h[13]+dx*b2f(s3.y);
        h[14]=dA[14]*h[14]+dx*b2f(s3.z); h[15]=dA[15]*h[15]+dx*b2f(s3.w);
      }
      float apv[16]; powers16(P, apv);
      #pragma unroll
      for (int q = 0; q < 4; q++){
        *(float4*)&ap[base + q*4] = *(float4*)&apv[q*4];
        *(float4*)&he[base + q*4] = *(float4*)&h[q*4];
      }
    } else {
      float apv[16];
      #pragma unroll
      for (int n = 0; n < 16; n++) apv[n] = 1.f;
      for (int t = 0; t < 32; t++){
        int row = rbase + t;
        float4 t4 = *(const float4*)&dtsh[row*4];
        float del = softplusf_(bd + t4.x*w0 + t4.y*w1 + t4.z*w2 + t4.w*w3);
        float xcv = b2f(xcB[row*136 + d]);
        float dx = del * xcv;
        #pragma unroll
        for (int n = 0; n < 16; n++){
          float dA = exp2f(del * A2[n]);
          apv[n] *= dA;
          h[n] = dA*h[n] + dx*b2f(BCL[row*32+n]);
        }
      }
      #pragma unroll
      for (int q = 0; q < 4; q++){
        *(float4*)&ap[base + q*4] = *(float4*)&apv[q*4];
        *(float4*)&he[base + q*4] = *(float4*)&h[q*4];
      }
    }
  }
  // final dump: zs, xc, BC -> global, coalesced short4 (stable since barrier 4)
  for (int i = tid; i < 1920; i += 256){
    *(short4v*)&zs[(size_t)row0*120 + i*4] = *(const short4v*)&zsL[i*4];
    int r = i/30, off = (i%30)*4;
    *(short4v*)&xcg[(size_t)(row0 + r)*120 + off] = *(const short4v*)&xcB[r*136 + off];
  }
  for (int i = tid; i < 512; i += 256)
    *(short4v*)&BCg[(size_t)row0*32 + i*4] = *(const short4v*)&BCL[i*4];
}

// =============== scan pass 2: hierarchical block-parallel chunk scan ===============
__global__ __launch_bounds__(256) void k_scan2(float* __restrict__ ap, const float* __restrict__ he)
{
  __shared__ float aggA[16*17];
  __shared__ float aggB[16*17];
  const int tid = threadIdx.x;
  const int n = tid & 15, j = tid >> 4;
  const int sbase = blockIdx.x*16 + n;
  const int stride = BATCH*DI*16;
  {
    float A = 1.f, B = 0.f;
    int idx = (j*32)*stride + sbase;
    #pragma unroll 4
    for (int k = 0; k < 32; k++){
      float a = ap[idx], h = he[idx];
      B = a*B + h;
      A *= a;
      idx += stride;
    }
    aggA[n*17 + j] = A;
    aggB[n*17 + j] = B;
  }
  __syncthreads();
  if (tid < 16){
    float B = 0.f;
    #pragma unroll
    for (int jj = 0; jj < 16; jj++){
      float Af = aggA[tid*17 + jj];
      float Bf = aggB[tid*17 + jj];
      aggB[tid*17 + jj] = B;
      B = Af*B + Bf;
    }
  }
  __syncthreads();
  {
    float H = aggB[n*17 + j];
    int idx = (j*32)*stride + sbase;
    #pragma unroll 4
    for (int k = 0; k < 32; k++){
      float a = ap[idx], h = he[idx];
      ap[idx] = H;
      H = a*H + h;
      idx += stride;
    }
  }
}

// =============== scan pass 3 + out_proj fused (bf16 in, bf16 hout) ===============
__global__ __launch_bounds__(128) void k_scan3o(
    const short* __restrict__ delta, const short* __restrict__ xc,
    const short* __restrict__ BCg, const short* __restrict__ zs,
    const float* __restrict__ h0, const float* __restrict__ A_log,
    const float* __restrict__ Dsk, const float* __restrict__ opw,
    short* __restrict__ hout)
{
  __shared__ float BCl[TCH*32];
  __shared__ float yL[TCH*124];
  const int tid = threadIdx.x;
  const int c = blockIdx.x % NCH, b = blockIdx.x / NCH;
  const size_t rowbase = (size_t)b*LSEQ + (size_t)c*TCH;
  for (int i = tid; i < TCH*32; i += 128)
    BCl[i] = b2f(BCg[rowbase*32 + i]);
  __syncthreads();
  const int d = tid;
  if (d < DI){
    float A2[16], h[16];
    int base = (c*BATCH + b)*(DI*16) + d*16;
    #pragma unroll
    for (int n = 0; n < 16; n++){
      A2[n] = -__expf(A_log[d*16+n]) * 1.44269504f;
      h[n] = h0[base+n];
    }
    bool fastp = true;
    #pragma unroll
    for (int n = 1; n < 16; n++)
      fastp = fastp && (fabsf(A2[n] - (n+1)*A2[0]) <= 1e-4f*fabsf(A2[n]));
    float Dv = Dsk[d];
    if (fastp){
      const float A20 = A2[0];
      for (int t = 0; t < TCH; t++){
        float del = b2f(delta[(rowbase+t)*DI + d]);
        float xcv = b2f(xc[(rowbase+t)*DI + d]);
        float zv  = b2f(zs[(rowbase+t)*DI + d]);
        float dx = del * xcv;
        float r = exp2f(del * A20);
        float dA[16]; powers16(r, dA);
        float4 b0 = *(const float4*)&BCl[t*32+0];
        float4 b1 = *(const float4*)&BCl[t*32+4];
        float4 b2 = *(const float4*)&BCl[t*32+8];
        float4 b3 = *(const float4*)&BCl[t*32+12];
        float4 c0 = *(const float4*)&BCl[t*32+16];
        float4 c1 = *(const float4*)&BCl[t*32+20];
        float4 c2 = *(const float4*)&BCl[t*32+24];
        float4 c3 = *(const float4*)&BCl[t*32+28];
        h[0]=dA[0]*h[0]+dx*b0.x;  h[1]=dA[1]*h[1]+dx*b0.y;  h[2]=dA[2]*h[2]+dx*b0.z;  h[3]=dA[3]*h[3]+dx*b0.w;
        h[4]=dA[4]*h[4]+dx*b1.x;  h[5]=dA[5]*h[5]+dx*b1.y;  h[6]=dA[6]*h[6]+dx*b1.z;  h[7]=dA[7]*h[7]+dx*b1.w;
        h[8]=dA[8]*h[8]+dx*b2.x;  h[9]=dA[9]*h[9]+dx*b2.y;  h[10]=dA[10]*h[10]+dx*b2.z; h[11]=dA[11]*h[11]+dx*b2.w;
        h[12]=dA[12]*h[12]+dx*b3.x; h[13]=dA[13]*h[13]+dx*b3.y; h[14]=dA[14]*h[14]+dx*b3.z; h[15]=dA[15]*h[15]+dx*b3.w;
        float acc = h[0]*c0.x + h[1]*c0.y + h[2]*c0.z + h[3]*c0.w
                  + h[4]*c1.x + h[5]*c1.y + h[6]*c1.z + h[7]*c1.w
                  + h[8]*c2.x + h[9]*c2.y + h[10]*c2.z + h[11]*c2.w
                  + h[12]*c3.x + h[13]*c3.y + h[14]*c3.z + h[15]*c3.w;
        yL[t*124 + d] = (acc + Dv*xcv) * zv;
      }
    } else {
      for (int t = 0; t < TCH; t++){
        float del = b2f(delta[(rowbase+t)*DI + d]);
        float xcv = b2f(xc[(rowbase+t)*DI + d]);
        float zv  = b2f(zs[(rowbase+t)*DI + d]);
        float dx = del * xcv;
        float acc = 0.f;
        #pragma unroll
        for (int n = 0; n < 16; n++){
          float dA = exp2f(del * A2[n]);
          h[n] = dA*h[n] + dx*BCl[t*32+n];
          acc += h[n]*BCl[t*32+16+n];
        }
        yL[t*124 + d] = (acc + Dv*xcv) * zv;
      }
    }
  }
  __syncthreads();
  if (tid < 120){
    const int cg = tid % 15, rg = tid / 15;
    float acc[4][4];
    #pragma unroll
    for (int r = 0; r < 4; r++){ acc[r][0]=0.f; acc[r][1]=0.f; acc[r][2]=0.f; acc[r][3]=0.f; }
    for (int kg = 0; kg < 30; kg++){
      int k = kg*4;
      float4 b0 = *(const float4*)&opw[(size_t)(cg*4+0)*120 + k];
      float4 b1 = *(const float4*)&opw[(size_t)(cg*4+1)*120 + k];
      float4 b2 = *(const float4*)&opw[(size_t)(cg*4+2)*120 + k];
      float4 b3 = *(const float4*)&opw[(size_t)(cg*4+3)*120 + k];
      #pragma unroll
      for (int r = 0; r < 4; r++){
        float4 a = *(const float4*)&yL[(rg*4+r)*124 + k];
        acc[r][0] += a.x*b0.x + a.y*b0.y + a.z*b0.z + a.w*b0.w;
        acc[r][1] += a.x*b1.x + a.y*b1.y + a.z*b1.z + a.w*b1.w;
        acc[r][2] += a.x*b2.x + a.y*b2.y + a.z*b2.z + a.w*b2.w;
        acc[r][3] += a.x*b3.x + a.y*b3.y + a.z*b3.z + a.w*b3.w;
      }
    }
    #pragma unroll
    for (int r = 0; r < 4; r++){
      short4v v;
      v.x = f2b(acc[r][0]); v.y = f2b(acc[r][1]); v.z = f2b(acc[r][2]); v.w = f2b(acc[r][3]);
      *(short4v*)&hout[(rowbase + rg*4 + r)*60 + cg*4] = v;
    }
  }
}

// =============== conv2d weight pack: w[co][ci][3][3] -> bf16 wB[tap][co64][ci64] ===============
__global__ __launch_bounds__(256) void k_wB(const float* __restrict__ w, short* __restrict__ wB)
{
  int i = blockIdx.x*256 + threadIdx.x;
  if (i >= 9*64*64) return;
  int ci = i & 63, co = (i >> 6) & 63, tap = i >> 12;
  float v = 0.f;
  if (co < 60 && ci < 60) v = w[((size_t)co*60 + ci)*9 + tap];
  wB[i] = f2b(v);
}

// =============== 3x3 SAME conv2d via bf16 MFMA + bias + residual ===============
__global__ __launch_bounds__(256) void k_conv2d(
    const short* __restrict__ hin, const short* __restrict__ wB,
    const float* __restrict__ cb, const float* __restrict__ xres,
    float* __restrict__ out)
{
  __shared__ short tile[3*66*72];
  const int tid = threadIdx.x;
  const int blk = blockIdx.x;
  const int xhalf = blk & 1;
  const int yy = (blk >> 1) & 127;
  const int b = blk >> 8;
  const int x0 = xhalf*64;
  for (int i = tid; i < 3*66*72; i += 256){
    int ci = i % 72;
    int xx = (i / 72) % 66;
    int row = i / (72*66);
    int gy = yy - 1 + row, gx = x0 - 1 + xx;
    short v = 0;
    if (ci < 60 && gy >= 0 && gy < HH && gx >= 0 && gx < WW)
      v = hin[((size_t)b*LSEQ + gy*WW + gx)*60 + ci];
    tile[i] = v;
  }
  __syncthreads();
  const int wave = tid >> 6, lane = tid & 63;
  const int m = lane & 15, quad = lane >> 4;
  f32x4 acc0 = {0.f,0.f,0.f,0.f}, acc1 = {0.f,0.f,0.f,0.f};
  f32x4 acc2 = {0.f,0.f,0.f,0.f}, acc3 = {0.f,0.f,0.f,0.f};
  #pragma unroll
  for (int tap = 0; tap < 9; tap++){
    const int ky = tap/3, kx = tap%3;
    const short* arow = &tile[(ky*66 + wave*16 + m + kx)*72];
    const short* brow = wB + tap*4096;
    #pragma unroll
    for (int kh = 0; kh < 2; kh++){
      const int k0 = kh*32 + quad*8;
      bhalf8 a = *(const bhalf8*)(arow + k0);
      bhalf8 b0 = *(const bhalf8*)(brow + (0*16 + m)*64 + k0);
      bhalf8 b1 = *(const bhalf8*)(brow + (1*16 + m)*64 + k0);
      bhalf8 b2 = *(const bhalf8*)(brow + (2*16 + m)*64 + k0);
      bhalf8 b3 = *(const bhalf8*)(brow + (3*16 + m)*64 + k0);
      acc0 = __builtin_amdgcn_mfma_f32_16x16x32_bf16(a, b0, acc0, 0, 0, 0);
      acc1 = __builtin_amdgcn_mfma_f32_16x16x32_bf16(a, b1, acc1, 0, 0, 0);
      acc2 = __builtin_amdgcn_mfma_f32_16x16x32_bf16(a, b2, acc2, 0, 0, 0);
      acc3 = __builtin_amdgcn_mfma_f32_16x16x32_bf16(a, b3, acc3, 0, 0, 0);
    }
  }
  const size_t rowb = (size_t)b*LSEQ + yy*WW + x0;
  f32x4 accs[4] = {acc0, acc1, acc2, acc3};
  #pragma unroll
  for (int nt = 0; nt < 4; nt++){
    int co = nt*16 + m;
    if (co < 60){
      float bias = cb[co];
      #pragma unroll
      for (int reg = 0; reg < 4; reg++){
        int px = wave*16 + quad*4 + reg;
        size_t o = (rowb + px)*60 + co;
        out[o] = accs[nt][reg] + bias + xres[o];
      }
    }
  }
}

extern "C" void kernel_launch(void* const* d_in, const int* in_sizes, int n_in,
                              void* d_out, int out_size, void* d_ws, size_t ws_size,
                              hipStream_t stream)
{
  const float* x      = (const float*)d_in[0];
  const float* ln_w   = (const float*)d_in[1];
  const float* ln_b   = (const float*)d_in[2];
  const float* ipw    = (const float*)d_in[3];
  const float* cw     = (const float*)d_in[4];
  const float* cb1    = (const float*)d_in[5];
  const float* xpw    = (const float*)d_in[6];
  const float* dtw    = (const float*)d_in[7];
  const float* dtb    = (const float*)d_in[8];
  const float* A_log  = (const float*)d_in[9];
  const float* Dsk    = (const float*)d_in[10];
  const float* opw    = (const float*)d_in[11];
  const float* c2w    = (const float*)d_in[12];
  const float* c2b    = (const float*)d_in[13];
  float* out = (float*)d_out;

  char* ws = (char*)d_ws;
  size_t off = 0;
  short* zsb   = (short*)(ws + off); off += (size_t)BATCH*LSEQ*DI*2;
  short* xcb   = (short*)(ws + off); off += (size_t)BATCH*LSEQ*DI*2;
  short* dlt   = (short*)(ws + off); off += (size_t)BATCH*LSEQ*DI*2;
  short* BCg   = (short*)(ws + off); off += (size_t)BATCH*LSEQ*32*2;
  float* apb   = (float*)(ws + off); off += (size_t)NCH*BATCH*DI*16*4;
  float* heb   = (float*)(ws + off); off += (size_t)NCH*BATCH*DI*16*4;
  short* hcur  = (short*)(ws + off); off += (size_t)BATCH*LSEQ*DM*2;
  short* wBb   = (short*)(ws + off); off += (size_t)9*64*64*2;
  short* pkb   = (short*)(ws + off); off += (size_t)(2*240*64 + 2*48*128)*2;

  const int rows = BATCH*LSEQ;
  k_pack<<<(2*240*64 + 2*48*128 + 255)/256, 256, 0, stream>>>(ipw, xpw, pkb);
  for (int layer = 0; layer < 2; layer++){
    const float* srcf = (layer == 0) ? x : nullptr;
    const short* srcb = (layer == 0) ? nullptr : hcur;
    k_lnxp<<<rows/64, 256, 0, stream>>>(srcf, srcb, ln_w + layer*DM, ln_b + layer*DM,
                                        pkb + (size_t)layer*240*64,
                                        cw + layer*DI*4, cb1 + layer*DI,
                                        pkb + 30720 + (size_t)layer*48*128,
                                        dtw + (size_t)layer*DI*4, dtb + layer*DI,
                                        A_log + (size_t)layer*DI*16,
                                        zsb, xcb, dlt, BCg, apb, heb);
    k_scan2<<<BATCH*DI, 256, 0, stream>>>(apb, heb);
    k_scan3o<<<BATCH*NCH, 128, 0, stream>>>(dlt, xcb, BCg, zsb, apb, A_log + (size_t)layer*DI*16,
                                            Dsk + layer*DI, opw + (size_t)layer*DM*DI, hcur);
  }
  k_wB<<<(9*64*64+255)/256, 256, 0, stream>>>(c2w, wBb);
  k_conv2d<<<BATCH*HH*2, 256, 0, stream>>>(hcur, wBb, c2b, x, out);
}

// Round 11
// 338.736 us; speedup vs baseline: 1.0217x; 1.0217x over previous
//
#include <hip/hip_runtime.h>
#include <math.h>

#define BATCH 2
#define LSEQ 16384
#define DM 60
#define DI 120
#define NCH 512
#define TCH 32    // LSEQ / NCH
#define HH 128
#define WW 128

typedef __attribute__((ext_vector_type(8))) short bhalf8;
typedef __attribute__((ext_vector_type(4))) short short4v;
typedef __attribute__((ext_vector_type(4))) float f32x4;

__device__ __forceinline__ float sigmoidf_(float x){ return __builtin_amdgcn_rcpf(1.0f + __expf(-x)); }
__device__ __forceinline__ float siluf_(float x){ return x * sigmoidf_(x); }
__device__ __forceinline__ float softplusf_(float x){ return (x > 20.0f) ? x : __logf(1.0f + __expf(x)); }
__device__ __forceinline__ short f2b(float f){   // RNE fp32->bf16 (finite inputs)
  union{float f; unsigned u;} v; v.f = f;
  unsigned r = (v.u + 0x7fffu + ((v.u >> 16) & 1u)) >> 16;
  return (short)r;
}
__device__ __forceinline__ float b2f(short s){
  union{float f; unsigned u;} v; v.u = ((unsigned)(unsigned short)s) << 16; return v.f;
}

// powers: dA[n] = r^(n+1), log-depth tree
__device__ __forceinline__ void powers16(float r, float* dA){
  dA[0] = r;
  #pragma unroll
  for (int n = 1; n < 16; n++) dA[n] = dA[(n-1)>>1] * dA[n>>1];
}

// ====== weight pre-pack: ipB = (lw∘ipw) bf16 [l][240][64]; xpB bf16 [l][48][128];
// ====== c01[l][240][2] = { c1=Σ lw∘W, c0=Σ lb∘W } fp32
__global__ __launch_bounds__(256) void k_pack(
    const float* __restrict__ ipw, const float* __restrict__ xpw,
    const float* __restrict__ lnw, const float* __restrict__ lnb,
    short* __restrict__ pk, float* __restrict__ c01)
{
  int i = blockIdx.x*256 + threadIdx.x;
  if (i < 2*240*64){
    int l = i / (240*64);
    int rem = i % (240*64);
    int n = rem / 64, k = rem % 64;
    float v = (k < 60) ? ipw[(size_t)l*14400 + n*60 + k] * lnw[l*60 + k] : 0.f;
    pk[i] = f2b(v);
  } else if (i < 30720 + 2*48*128){
    int j = i - 30720;
    int l = j / (48*128);
    int rem = j % (48*128);
    int n = rem / 128, k = rem % 128;
    float v = (n < 36 && k < 120) ? xpw[(size_t)l*36*120 + n*120 + k] : 0.f;
    pk[i] = f2b(v);
  } else if (i < 43008 + 480){
    int j = i - 43008;
    int l = j / 240, n = j % 240;
    float c1 = 0.f, c0 = 0.f;
    for (int k = 0; k < 60; k++){
      float w = ipw[(size_t)l*14400 + n*60 + k];
      c1 += lnw[l*60+k] * w;
      c0 += lnb[l*60+k] * w;
    }
    c01[(l*240 + n)*2 + 0] = c1;
    c01[(l*240 + n)*2 + 1] = c0;
  }
}

// ====== fused [LN-folded in_proj](MFMA, stats via MFMA) + conv1d + x_proj(MFMA)
// ====== + dt_proj + chunk-scan. 64 rows (2 chunks) per block; halo 3.
__global__ __launch_bounds__(256) void k_lnxp(
    const float* __restrict__ srcf, const short* __restrict__ srcb,
    const short* __restrict__ ipB,   // [240][64] bf16 (lw-folded)
    const float* __restrict__ c01,   // [240][2] fp32 {c1,c0}
    const float* __restrict__ cw, const float* __restrict__ cb,
    const short* __restrict__ xpB,   // [48][128] bf16
    const float* __restrict__ dtw, const float* __restrict__ dtb,
    const float* __restrict__ A_log,
    short* __restrict__ zs, short* __restrict__ xcg,
    short* __restrict__ delta, short* __restrict__ BCg,
    float* __restrict__ ap, float* __restrict__ he)
{
  __shared__ __align__(16) char smem[52128];
  short* XB   = (short*)smem;            // [80][72] bf16 raw x (phase 0-2); xcB aliases
  short* xcB  = (short*)smem;            // [64][136] bf16 (phase 3+)
  short* xinB = (short*)(smem + 17408);  // [80][136] bf16; first 11520 B = XSQ in phase 0-2
  short* XSQ  = (short*)(smem + 17408);  // [80][72] bf16 x^2
  short* BCL  = (short*)(smem + 39168);  // [64][32] bf16
  float* stats= (float*)(smem + 43264);  // [80][2]: raw {Sx,Sq} then {mu,rs}
  float* dtsh = (float*)(smem + 43904);  // [64][4]
  float* cwL  = (float*)(smem + 44928);  // [120][4]
  float* Wd5  = (float*)(smem + 46848);  // [120][5]
  float* cbL  = (float*)(smem + 49248);  // [120]
  float* bdL  = (float*)(smem + 49728);  // [120]
  float* c01L = (float*)(smem + 50208);  // [240][2]
  const int tid = threadIdx.x;
  const int wave = tid >> 6, lane = tid & 63;
  const int m = lane & 15, quad = lane >> 4;
  const int row0 = blockIdx.x * 64;
  const int seq0 = (row0 / LSEQ) * LSEQ;
  // phase 0: consts + stage raw X and X^2 (bf16), halo/pad rows = 0
  for (int i = tid; i < 480; i += 256){ cwL[i] = cw[i]; Wd5[(i/4)*5 + (i%4)] = dtw[i]; c01L[i] = c01[i]; }
  for (int i = tid; i < 120; i += 256){ cbL[i] = cb[i]; bdL[i] = dtb[i]; }
  for (int i = tid; i < 80*60; i += 256){
    int r = i/60, c = i%60;
    int grow = row0 - 3 + r;
    bool valid = (r < 67) && (grow >= seq0);
    float v = 0.f;
    if (valid) v = srcb ? b2f(srcb[(size_t)grow*60 + c]) : srcf[(size_t)grow*60 + c];
    XB[r*72 + c]  = f2b(v);
    XSQ[r*72 + c] = f2b(v*v);
  }
  for (int i = tid; i < 80*12; i += 256){
    int r = i/12, c = 60 + i%12;
    XB[r*72 + c] = 0; XSQ[r*72 + c] = 0;
  }
  __syncthreads();
  // phase 1a: row stats via MFMA against ones-column B
  {
    bhalf8 bones;
    #pragma unroll
    for (int j = 0; j < 8; j++) bones[j] = (m == 0) ? (short)0x3F80 : (short)0;
    for (int t = wave; t < 5; t += 4){
      f32x4 as = {0.f,0.f,0.f,0.f}, aq = {0.f,0.f,0.f,0.f};
      #pragma unroll
      for (int ks = 0; ks < 2; ks++){
        bhalf8 ax = *(const bhalf8*)&XB[(t*16 + m)*72 + ks*32 + quad*8];
        bhalf8 a2 = *(const bhalf8*)&XSQ[(t*16 + m)*72 + ks*32 + quad*8];
        as = __builtin_amdgcn_mfma_f32_16x16x32_bf16(ax, bones, as, 0, 0, 0);
        aq = __builtin_amdgcn_mfma_f32_16x16x32_bf16(a2, bones, aq, 0, 0, 0);
      }
      if (m == 0){
        #pragma unroll
        for (int reg = 0; reg < 4; reg++){
          int r = t*16 + quad*4 + reg;
          stats[r*2 + 0] = as[reg];
          stats[r*2 + 1] = aq[reg];
        }
      }
    }
  }
  __syncthreads();
  // phase 1b: convert sums -> mu, rs
  if (tid < 80){
    float Sx = stats[tid*2], Sq = stats[tid*2+1];
    float mu = Sx * (1.0f/60.0f);
    float var = fmaxf(Sq * (1.0f/60.0f) - mu*mu, 0.f);
    stats[tid*2] = mu;
    stats[tid*2+1] = rsqrtf(var + 1e-5f);
  }
  __syncthreads();
  // phase 2: in_proj MFMA on raw X + LN fixup in epilogue; zs direct to global
  for (int t = wave; t < 75; t += 4){
    int mtile = t / 15, ntile = t % 15;
    f32x4 acc = {0.f,0.f,0.f,0.f};
    #pragma unroll
    for (int ks = 0; ks < 2; ks++){
      bhalf8 a = *(const bhalf8*)&XB[(mtile*16 + m)*72 + ks*32 + quad*8];
      bhalf8 b = *(const bhalf8*)&ipB[(ntile*16 + m)*64 + ks*32 + quad*8];
      acc = __builtin_amdgcn_mfma_f32_16x16x32_bf16(a, b, acc, 0, 0, 0);
    }
    int n = ntile*16 + m;
    float c1v = c01L[n*2], c0v = c01L[n*2+1];
    #pragma unroll
    for (int reg = 0; reg < 4; reg++){
      int r = mtile*16 + quad*4 + reg;
      int grow = row0 - 3 + r;
      bool valid = (r < 67) && (grow >= seq0);
      float mu = stats[r*2], rs = stats[r*2+1];
      float val = rs*(acc[reg] - mu*c1v) + c0v;
      if (!valid) val = 0.f;
      if (n < 120){
        xinB[r*136 + n] = f2b(val);
      } else if (r >= 3 && r < 67){
        zs[(size_t)(row0 - 3 + r)*120 + (n - 120)] = f2b(siluf_(val));
      }
    }
  }
  __syncthreads();
  // phase 3: conv1d(4 taps)+silu -> xcB bf16 (K-pad 120..127 = 0)
  #pragma unroll
  for (int j = 0; j < 30; j++){
    int i = tid + j*256;
    int r = i/120, c = i%120;
    float a = cbL[c];
    #pragma unroll
    for (int k = 0; k < 4; k++)
      a += cwL[c*4+k] * b2f(xinB[(r+k)*136 + c]);
    a = siluf_(a);
    xcB[r*136 + c] = f2b(a);
  }
  for (int i = tid; i < 64*8; i += 256)
    xcB[(i >> 3)*136 + 120 + (i & 7)] = 0;
  __syncthreads();
  // phase 4: x_proj MFMA: wave w -> mtile w; 3 ntiles; K=128; dt->dtsh, B/C->BCL
  {
    f32x4 acc0 = {0.f,0.f,0.f,0.f}, acc1 = {0.f,0.f,0.f,0.f}, acc2 = {0.f,0.f,0.f,0.f};
    #pragma unroll
    for (int ks = 0; ks < 4; ks++){
      bhalf8 a  = *(const bhalf8*)&xcB[(wave*16 + m)*136 + ks*32 + quad*8];
      bhalf8 b0 = *(const bhalf8*)&xpB[(0*16 + m)*128 + ks*32 + quad*8];
      bhalf8 b1 = *(const bhalf8*)&xpB[(1*16 + m)*128 + ks*32 + quad*8];
      bhalf8 b2 = *(const bhalf8*)&xpB[(2*16 + m)*128 + ks*32 + quad*8];
      acc0 = __builtin_amdgcn_mfma_f32_16x16x32_bf16(a, b0, acc0, 0, 0, 0);
      acc1 = __builtin_amdgcn_mfma_f32_16x16x32_bf16(a, b1, acc1, 0, 0, 0);
      acc2 = __builtin_amdgcn_mfma_f32_16x16x32_bf16(a, b2, acc2, 0, 0, 0);
    }
    f32x4 accs[3] = {acc0, acc1, acc2};
    #pragma unroll
    for (int nt = 0; nt < 3; nt++){
      int n = nt*16 + m;
      #pragma unroll
      for (int reg = 0; reg < 4; reg++){
        int r = wave*16 + quad*4 + reg;
        float val = accs[nt][reg];
        if (n < 4)       dtsh[r*4 + n] = val;
        else if (n < 36) BCL[r*32 + (n - 4)] = f2b(val);
      }
    }
  }
  __syncthreads();
  // ---- no more barriers below ----
  // phase 5: dt_proj + softplus -> delta global (bf16, coalesced)
  #pragma unroll
  for (int j = 0; j < 30; j++){
    int i = tid + j*256;
    int row = i/120, d = i%120;
    float t0 = dtsh[row*4], t1 = dtsh[row*4+1], t2 = dtsh[row*4+2], t3 = dtsh[row*4+3];
    float a = bdL[d] + t0*Wd5[d*5] + t1*Wd5[d*5+1] + t2*Wd5[d*5+2] + t3*Wd5[d*5+3];
    delta[(size_t)(row0 + row)*120 + d] = f2b(softplusf_(a));
  }
  // phase 6: fused scan pass 1 over this block's two 32-row chunks
  if (tid < 240){
    const int cc = tid / 120, d = tid % 120;
    const int b = row0 / LSEQ;
    const int cglob = ((row0 % LSEQ) >> 5) + cc;
    float A2[16], h[16];
    #pragma unroll
    for (int n = 0; n < 16; n++){ A2[n] = -__expf(A_log[d*16+n]) * 1.44269504f; h[n] = 0.f; }
    bool fastp = true;
    #pragma unroll
    for (int n = 1; n < 16; n++)
      fastp = fastp && (fabsf(A2[n] - (n+1)*A2[0]) <= 1e-4f*fabsf(A2[n]));
    const float w0 = Wd5[d*5], w1 = Wd5[d*5+1], w2 = Wd5[d*5+2], w3 = Wd5[d*5+3];
    const float bd = bdL[d];
    const int rbase = cc*32;
    int base = (cglob*BATCH + b)*(DI*16) + d*16;
    if (fastp){
      float P = 1.f;
      const float A20 = A2[0];
      for (int t = 0; t < 32; t++){
        int row = rbase + t;
        float4 t4 = *(const float4*)&dtsh[row*4];
        float del = softplusf_(bd + t4.x*w0 + t4.y*w1 + t4.z*w2 + t4.w*w3);
        float xcv = b2f(xcB[row*136 + d]);
        float dx = del * xcv;
        float r = exp2f(del * A20);
        P *= r;
        float dA[16]; powers16(r, dA);
        short4v s0 = *(const short4v*)&BCL[row*32+0];
        short4v s1 = *(const short4v*)&BCL[row*32+4];
        short4v s2 = *(const short4v*)&BCL[row*32+8];
        short4v s3 = *(const short4v*)&BCL[row*32+12];
        h[0]=dA[0]*h[0]+dx*b2f(s0.x);  h[1]=dA[1]*h[1]+dx*b2f(s0.y);
        h[2]=dA[2]*h[2]+dx*b2f(s0.z);  h[3]=dA[3]*h[3]+dx*b2f(s0.w);
        h[4]=dA[4]*h[4]+dx*b2f(s1.x);  h[5]=dA[5]*h[5]+dx*b2f(s1.y);
        h[6]=dA[6]*h[6]+dx*b2f(s1.z);  h[7]=dA[7]*h[7]+dx*b2f(s1.w);
        h[8]=dA[8]*h[8]+dx*b2f(s2.x);  h[9]=dA[9]*h[9]+dx*b2f(s2.y);
        h[10]=dA[10]*h[10]+dx*b2f(s2.z); h[11]=dA[11]*h[11]+dx*b2f(s2.w);
        h[12]=dA[12]*h[12]+dx*b2f(s3.x); h[13]=dA[13]*h[13]+dx*b2f(s3.y);
        h[14]=dA[14]*h[14]+dx*b2f(s3.z); h[15]=dA[15]*h[15]+dx*b2f(s3.w);
      }
      float apv[16]; powers16(P, apv);
      #pragma unroll
      for (int q = 0; q < 4; q++){
        *(float4*)&ap[base + q*4] = *(float4*)&apv[q*4];
        *(float4*)&he[base + q*4] = *(float4*)&h[q*4];
      }
    } else {
      float apv[16];
      #pragma unroll
      for (int n = 0; n < 16; n++) apv[n] = 1.f;
      for (int t = 0; t < 32; t++){
        int row = rbase + t;
        float4 t4 = *(const float4*)&dtsh[row*4];
        float del = softplusf_(bd + t4.x*w0 + t4.y*w1 + t4.z*w2 + t4.w*w3);
        float xcv = b2f(xcB[row*136 + d]);
        float dx = del * xcv;
        #pragma unroll
        for (int n = 0; n < 16; n++){
          float dA = exp2f(del * A2[n]);
          apv[n] *= dA;
          h[n] = dA*h[n] + dx*b2f(BCL[row*32+n]);
        }
      }
      #pragma unroll
      for (int q = 0; q < 4; q++){
        *(float4*)&ap[base + q*4] = *(float4*)&apv[q*4];
        *(float4*)&he[base + q*4] = *(float4*)&h[q*4];
      }
    }
  }
  // final dump: xc, BC -> global, coalesced short4
  for (int i = tid; i < 1920; i += 256){
    int r = i/30, off = (i%30)*4;
    *(short4v*)&xcg[(size_t)(row0 + r)*120 + off] = *(const short4v*)&xcB[r*136 + off];
  }
  for (int i = tid; i < 512; i += 256)
    *(short4v*)&BCg[(size_t)row0*32 + i*4] = *(const short4v*)&BCL[i*4];
}

// =============== scan pass 2: hierarchical block-parallel chunk scan ===============
__global__ __launch_bounds__(256) void k_scan2(float* __restrict__ ap, const float* __restrict__ he)
{
  __shared__ float aggA[16*17];
  __shared__ float aggB[16*17];
  const int tid = threadIdx.x;
  const int n = tid & 15, j = tid >> 4;
  const int sbase = blockIdx.x*16 + n;
  const int stride = BATCH*DI*16;
  {
    float A = 1.f, B = 0.f;
    int idx = (j*32)*stride + sbase;
    #pragma unroll 4
    for (int k = 0; k < 32; k++){
      float a = ap[idx], h = he[idx];
      B = a*B + h;
      A *= a;
      idx += stride;
    }
    aggA[n*17 + j] = A;
    aggB[n*17 + j] = B;
  }
  __syncthreads();
  if (tid < 16){
    float B = 0.f;
    #pragma unroll
    for (int jj = 0; jj < 16; jj++){
      float Af = aggA[tid*17 + jj];
      float Bf = aggB[tid*17 + jj];
      aggB[tid*17 + jj] = B;
      B = Af*B + Bf;
    }
  }
  __syncthreads();
  {
    float H = aggB[n*17 + j];
    int idx = (j*32)*stride + sbase;
    #pragma unroll 4
    for (int k = 0; k < 32; k++){
      float a = ap[idx], h = he[idx];
      ap[idx] = H;
      H = a*H + h;
      idx += stride;
    }
  }
}

// =============== scan pass 3 + out_proj fused (bf16 in, bf16 hout) ===============
__global__ __launch_bounds__(128) void k_scan3o(
    const short* __restrict__ delta, const short* __restrict__ xc,
    const short* __restrict__ BCg, const short* __restrict__ zs,
    const float* __restrict__ h0, const float* __restrict__ A_log,
    const float* __restrict__ Dsk, const float* __restrict__ opw,
    short* __restrict__ hout)
{
  __shared__ float BCl[TCH*32];
  __shared__ float yL[TCH*124];
  const int tid = threadIdx.x;
  const int c = blockIdx.x % NCH, b = blockIdx.x / NCH;
  const size_t rowbase = (size_t)b*LSEQ + (size_t)c*TCH;
  for (int i = tid; i < TCH*32; i += 128)
    BCl[i] = b2f(BCg[rowbase*32 + i]);
  __syncthreads();
  const int d = tid;
  if (d < DI){
    float A2[16], h[16];
    int base = (c*BATCH + b)*(DI*16) + d*16;
    #pragma unroll
    for (int n = 0; n < 16; n++){
      A2[n] = -__expf(A_log[d*16+n]) * 1.44269504f;
      h[n] = h0[base+n];
    }
    bool fastp = true;
    #pragma unroll
    for (int n = 1; n < 16; n++)
      fastp = fastp && (fabsf(A2[n] - (n+1)*A2[0]) <= 1e-4f*fabsf(A2[n]));
    float Dv = Dsk[d];
    if (fastp){
      const float A20 = A2[0];
      for (int t = 0; t < TCH; t++){
        float del = b2f(delta[(rowbase+t)*DI + d]);
        float xcv = b2f(xc[(rowbase+t)*DI + d]);
        float zv  = b2f(zs[(rowbase+t)*DI + d]);
        float dx = del * xcv;
        float r = exp2f(del * A20);
        float dA[16]; powers16(r, dA);
        float4 b0 = *(const float4*)&BCl[t*32+0];
        float4 b1 = *(const float4*)&BCl[t*32+4];
        float4 b2 = *(const float4*)&BCl[t*32+8];
        float4 b3 = *(const float4*)&BCl[t*32+12];
        float4 c0 = *(const float4*)&BCl[t*32+16];
        float4 c1 = *(const float4*)&BCl[t*32+20];
        float4 c2 = *(const float4*)&BCl[t*32+24];
        float4 c3 = *(const float4*)&BCl[t*32+28];
        h[0]=dA[0]*h[0]+dx*b0.x;  h[1]=dA[1]*h[1]+dx*b0.y;  h[2]=dA[2]*h[2]+dx*b0.z;  h[3]=dA[3]*h[3]+dx*b0.w;
        h[4]=dA[4]*h[4]+dx*b1.x;  h[5]=dA[5]*h[5]+dx*b1.y;  h[6]=dA[6]*h[6]+dx*b1.z;  h[7]=dA[7]*h[7]+dx*b1.w;
        h[8]=dA[8]*h[8]+dx*b2.x;  h[9]=dA[9]*h[9]+dx*b2.y;  h[10]=dA[10]*h[10]+dx*b2.z; h[11]=dA[11]*h[11]+dx*b2.w;
        h[12]=dA[12]*h[12]+dx*b3.x; h[13]=dA[13]*h[13]+dx*b3.y; h[14]=dA[14]*h[14]+dx*b3.z; h[15]=dA[15]*h[15]+dx*b3.w;
        float acc = h[0]*c0.x + h[1]*c0.y + h[2]*c0.z + h[3]*c0.w
                  + h[4]*c1.x + h[5]*c1.y + h[6]*c1.z + h[7]*c1.w
                  + h[8]*c2.x + h[9]*c2.y + h[10]*c2.z + h[11]*c2.w
                  + h[12]*c3.x + h[13]*c3.y + h[14]*c3.z + h[15]*c3.w;
        yL[t*124 + d] = (acc + Dv*xcv) * zv;
      }
    } else {
      for (int t = 0; t < TCH; t++){
        float del = b2f(delta[(rowbase+t)*DI + d]);
        float xcv = b2f(xc[(rowbase+t)*DI + d]);
        float zv  = b2f(zs[(rowbase+t)*DI + d]);
        float dx = del * xcv;
        float acc = 0.f;
        #pragma unroll
        for (int n = 0; n < 16; n++){
          float dA = exp2f(del * A2[n]);
          h[n] = dA*h[n] + dx*BCl[t*32+n];
          acc += h[n]*BCl[t*32+16+n];
        }
        yL[t*124 + d] = (acc + Dv*xcv) * zv;
      }
    }
  }
  __syncthreads();
  if (tid < 120){
    const int cg = tid % 15, rg = tid / 15;
    float acc[4][4];
    #pragma unroll
    for (int r = 0; r < 4; r++){ acc[r][0]=0.f; acc[r][1]=0.f; acc[r][2]=0.f; acc[r][3]=0.f; }
    for (int kg = 0; kg < 30; kg++){
      int k = kg*4;
      float4 b0 = *(const float4*)&opw[(size_t)(cg*4+0)*120 + k];
      float4 b1 = *(const float4*)&opw[(size_t)(cg*4+1)*120 + k];
      float4 b2 = *(const float4*)&opw[(size_t)(cg*4+2)*120 + k];
      float4 b3 = *(const float4*)&opw[(size_t)(cg*4+3)*120 + k];
      #pragma unroll
      for (int r = 0; r < 4; r++){
        float4 a = *(const float4*)&yL[(rg*4+r)*124 + k];
        acc[r][0] += a.x*b0.x + a.y*b0.y + a.z*b0.z + a.w*b0.w;
        acc[r][1] += a.x*b1.x + a.y*b1.y + a.z*b1.z + a.w*b1.w;
        acc[r][2] += a.x*b2.x + a.y*b2.y + a.z*b2.z + a.w*b2.w;
        acc[r][3] += a.x*b3.x + a.y*b3.y + a.z*b3.z + a.w*b3.w;
      }
    }
    #pragma unroll
    for (int r = 0; r < 4; r++){
      short4v v;
      v.x = f2b(acc[r][0]); v.y = f2b(acc[r][1]); v.z = f2b(acc[r][2]); v.w = f2b(acc[r][3]);
      *(short4v*)&hout[(rowbase + rg*4 + r)*60 + cg*4] = v;
    }
  }
}

// =============== conv2d weight pack: w[co][ci][3][3] -> bf16 wB[tap][co64][ci64] ===============
__global__ __launch_bounds__(256) void k_wB(const float* __restrict__ w, short* __restrict__ wB)
{
  int i = blockIdx.x*256 + threadIdx.x;
  if (i >= 9*64*64) return;
  int ci = i & 63, co = (i >> 6) & 63, tap = i >> 12;
  float v = 0.f;
  if (co < 60 && ci < 60) v = w[((size_t)co*60 + ci)*9 + tap];
  wB[i] = f2b(v);
}

// =============== 3x3 SAME conv2d via bf16 MFMA + bias + residual ===============
__global__ __launch_bounds__(256) void k_conv2d(
    const short* __restrict__ hin, const short* __restrict__ wB,
    const float* __restrict__ cb, const float* __restrict__ xres,
    float* __restrict__ out)
{
  __shared__ short tile[3*66*72];
  const int tid = threadIdx.x;
  const int blk = blockIdx.x;
  const int xhalf = blk & 1;
  const int yy = (blk >> 1) & 127;
  const int b = blk >> 8;
  const int x0 = xhalf*64;
  for (int i = tid; i < 3*66*72; i += 256){
    int ci = i % 72;
    int xx = (i / 72) % 66;
    int row = i / (72*66);
    int gy = yy - 1 + row, gx = x0 - 1 + xx;
    short v = 0;
    if (ci < 60 && gy >= 0 && gy < HH && gx >= 0 && gx < WW)
      v = hin[((size_t)b*LSEQ + gy*WW + gx)*60 + ci];
    tile[i] = v;
  }
  __syncthreads();
  const int wave = tid >> 6, lane = tid & 63;
  const int m = lane & 15, quad = lane >> 4;
  f32x4 acc0 = {0.f,0.f,0.f,0.f}, acc1 = {0.f,0.f,0.f,0.f};
  f32x4 acc2 = {0.f,0.f,0.f,0.f}, acc3 = {0.f,0.f,0.f,0.f};
  #pragma unroll
  for (int tap = 0; tap < 9; tap++){
    const int ky = tap/3, kx = tap%3;
    const short* arow = &tile[(ky*66 + wave*16 + m + kx)*72];
    const short* brow = wB + tap*4096;
    #pragma unroll
    for (int kh = 0; kh < 2; kh++){
      const int k0 = kh*32 + quad*8;
      bhalf8 a = *(const bhalf8*)(arow + k0);
      bhalf8 b0 = *(const bhalf8*)(brow + (0*16 + m)*64 + k0);
      bhalf8 b1 = *(const bhalf8*)(brow + (1*16 + m)*64 + k0);
      bhalf8 b2 = *(const bhalf8*)(brow + (2*16 + m)*64 + k0);
      bhalf8 b3 = *(const bhalf8*)(brow + (3*16 + m)*64 + k0);
      acc0 = __builtin_amdgcn_mfma_f32_16x16x32_bf16(a, b0, acc0, 0, 0, 0);
      acc1 = __builtin_amdgcn_mfma_f32_16x16x32_bf16(a, b1, acc1, 0, 0, 0);
      acc2 = __builtin_amdgcn_mfma_f32_16x16x32_bf16(a, b2, acc2, 0, 0, 0);
      acc3 = __builtin_amdgcn_mfma_f32_16x16x32_bf16(a, b3, acc3, 0, 0, 0);
    }
  }
  const size_t rowb = (size_t)b*LSEQ + yy*WW + x0;
  f32x4 accs[4] = {acc0, acc1, acc2, acc3};
  #pragma unroll
  for (int nt = 0; nt < 4; nt++){
    int co = nt*16 + m;
    if (co < 60){
      float bias = cb[co];
      #pragma unroll
      for (int reg = 0; reg < 4; reg++){
        int px = wave*16 + quad*4 + reg;
        size_t o = (rowb + px)*60 + co;
        out[o] = accs[nt][reg] + bias + xres[o];
      }
    }
  }
}

extern "C" void kernel_launch(void* const* d_in, const int* in_sizes, int n_in,
                              void* d_out, int out_size, void* d_ws, size_t ws_size,
                              hipStream_t stream)
{
  const float* x      = (const float*)d_in[0];
  const float* ln_w   = (const float*)d_in[1];
  const float* ln_b   = (const float*)d_in[2];
  const float* ipw    = (const float*)d_in[3];
  const float* cw     = (const float*)d_in[4];
  const float* cb1    = (const float*)d_in[5];
  const float* xpw    = (const float*)d_in[6];
  const float* dtw    = (const float*)d_in[7];
  const float* dtb    = (const float*)d_in[8];
  const float* A_log  = (const float*)d_in[9];
  const float* Dsk    = (const float*)d_in[10];
  const float* opw    = (const float*)d_in[11];
  const float* c2w    = (const float*)d_in[12];
  const float* c2b    = (const float*)d_in[13];
  float* out = (float*)d_out;

  char* ws = (char*)d_ws;
  size_t off = 0;
  short* zsb   = (short*)(ws + off); off += (size_t)BATCH*LSEQ*DI*2;
  short* xcb   = (short*)(ws + off); off += (size_t)BATCH*LSEQ*DI*2;
  short* dlt   = (short*)(ws + off); off += (size_t)BATCH*LSEQ*DI*2;
  short* BCg   = (short*)(ws + off); off += (size_t)BATCH*LSEQ*32*2;
  float* apb   = (float*)(ws + off); off += (size_t)NCH*BATCH*DI*16*4;
  float* heb   = (float*)(ws + off); off += (size_t)NCH*BATCH*DI*16*4;
  short* hcur  = (short*)(ws + off); off += (size_t)BATCH*LSEQ*DM*2;
  short* wBb   = (short*)(ws + off); off += (size_t)9*64*64*2;
  short* pkb   = (short*)(ws + off); off += (size_t)(2*240*64 + 2*48*128)*2;
  float* c01b  = (float*)(ws + off); off += (size_t)2*240*2*4;

  const int rows = BATCH*LSEQ;
  k_pack<<<(43008 + 480 + 255)/256, 256, 0, stream>>>(ipw, xpw, ln_w, ln_b, pkb, c01b);
  for (int layer = 0; layer < 2; layer++){
    const float* srcf = (layer == 0) ? x : nullptr;
    const short* srcb = (layer == 0) ? nullptr : hcur;
    k_lnxp<<<rows/64, 256, 0, stream>>>(srcf, srcb,
                                        pkb + (size_t)layer*240*64,
                                        c01b + (size_t)layer*240*2,
                                        cw + layer*DI*4, cb1 + layer*DI,
                                        pkb + 30720 + (size_t)layer*48*128,
                                        dtw + (size_t)layer*DI*4, dtb + layer*DI,
                                        A_log + (size_t)layer*DI*16,
                                        zsb, xcb, dlt, BCg, apb, heb);
    k_scan2<<<BATCH*DI, 256, 0, stream>>>(apb, heb);
    k_scan3o<<<BATCH*NCH, 128, 0, stream>>>(dlt, xcb, BCg, zsb, apb, A_log + (size_t)layer*DI*16,
                                            Dsk + layer*DI, opw + (size_t)layer*DM*DI, hcur);
  }
  k_wB<<<(9*64*64+255)/256, 256, 0, stream>>>(c2w, wBb);
  k_conv2d<<<BATCH*HH*2, 256, 0, stream>>>(hcur, wBb, c2b, x, out);
}

// Round 12
// 318.252 us; speedup vs baseline: 1.0875x; 1.0644x over previous
//
#include <hip/hip_runtime.h>
#include <math.h>

#define BATCH 2
#define LSEQ 16384
#define DM 60
#define DI 120
#define NCH 512
#define TCH 32    // LSEQ / NCH
#define HH 128
#define WW 128

typedef __attribute__((ext_vector_type(8))) short bhalf8;
typedef __attribute__((ext_vector_type(4))) short short4v;
typedef __attribute__((ext_vector_type(4))) float f32x4;

__device__ __forceinline__ float sigmoidf_(float x){ return __builtin_amdgcn_rcpf(1.0f + __expf(-x)); }
__device__ __forceinline__ float siluf_(float x){ return x * sigmoidf_(x); }
__device__ __forceinline__ float softplusf_(float x){ return (x > 20.0f) ? x : __logf(1.0f + __expf(x)); }
__device__ __forceinline__ short f2b(float f){   // RNE fp32->bf16 (finite inputs)
  union{float f; unsigned u;} v; v.f = f;
  unsigned r = (v.u + 0x7fffu + ((v.u >> 16) & 1u)) >> 16;
  return (short)r;
}
__device__ __forceinline__ float b2f(short s){
  union{float f; unsigned u;} v; v.u = ((unsigned)(unsigned short)s) << 16; return v.f;
}

// powers: dA[n] = r^(n+1), log-depth tree
__device__ __forceinline__ void powers16(float r, float* dA){
  dA[0] = r;
  #pragma unroll
  for (int n = 1; n < 16; n++) dA[n] = dA[(n-1)>>1] * dA[n>>1];
}

// ====== weight pre-pack: ipB = (lw∘ipw) bf16 [l][240][64]; xpB bf16 [l][48][128];
// ====== c01[l][240][2] = { c1=Σ lw∘W, c0=Σ lb∘W } fp32
__global__ __launch_bounds__(256) void k_pack(
    const float* __restrict__ ipw, const float* __restrict__ xpw,
    const float* __restrict__ lnw, const float* __restrict__ lnb,
    short* __restrict__ pk, float* __restrict__ c01)
{
  int i = blockIdx.x*256 + threadIdx.x;
  if (i < 2*240*64){
    int l = i / (240*64);
    int rem = i % (240*64);
    int n = rem / 64, k = rem % 64;
    float v = (k < 60) ? ipw[(size_t)l*14400 + n*60 + k] * lnw[l*60 + k] : 0.f;
    pk[i] = f2b(v);
  } else if (i < 30720 + 2*48*128){
    int j = i - 30720;
    int l = j / (48*128);
    int rem = j % (48*128);
    int n = rem / 128, k = rem % 128;
    float v = (n < 36 && k < 120) ? xpw[(size_t)l*36*120 + n*120 + k] : 0.f;
    pk[i] = f2b(v);
  } else if (i < 43008 + 480){
    int j = i - 43008;
    int l = j / 240, n = j % 240;
    float c1 = 0.f, c0 = 0.f;
    for (int k = 0; k < 60; k++){
      float w = ipw[(size_t)l*14400 + n*60 + k];
      c1 += lnw[l*60+k] * w;
      c0 += lnb[l*60+k] * w;
    }
    c01[(l*240 + n)*2 + 0] = c1;
    c01[(l*240 + n)*2 + 1] = c0;
  }
}

// ====== fused [LN-folded in_proj](MFMA) + conv1d + x_proj(MFMA) + dt_proj + chunk-scan
// ====== 32 rows = ONE scan chunk per block; halo 3; 1024 blocks (4/CU).
__global__ __launch_bounds__(256) void k_lnxp(
    const float* __restrict__ srcf, const short* __restrict__ srcb,
    const short* __restrict__ ipB,   // [240][64] bf16 (lw-folded)
    const float* __restrict__ c01,   // [240][2] fp32 {c1,c0}
    const float* __restrict__ cw, const float* __restrict__ cb,
    const short* __restrict__ xpB,   // [48][128] bf16
    const float* __restrict__ dtw, const float* __restrict__ dtb,
    const float* __restrict__ A_log,
    short* __restrict__ zs, short* __restrict__ xcg,
    short* __restrict__ delta, short* __restrict__ BCg,
    float* __restrict__ ap, float* __restrict__ he)
{
  __shared__ __align__(16) char smem[39072];
  short* XB   = (short*)smem;            // [48][72] bf16 (phase 0-2); xcB aliases
  short* xcB  = (short*)smem;            // [32][136] bf16 (phase 3+)
  short* XSQ  = (short*)(smem + 6912);   // [48][72] bf16 x^2
  short* xinB = (short*)(smem + 13824);  // [48][136] bf16
  float* BLf  = (float*)(smem + 26880);  // [32][16] fp32 B for scan
  short* BCL  = (short*)(smem + 28928);  // [32][32] bf16 (global dump)
  float* stats= (float*)(smem + 30976);  // [48][2]: {Sx,Sq} then {mu,rs}
  float* dtsh = (float*)(smem + 31360);  // [32][4]
  float* cwL  = (float*)(smem + 31872);  // [120][4]
  float* Wd5  = (float*)(smem + 33792);  // [120][5]
  float* cbL  = (float*)(smem + 36192);  // [120]
  float* bdL  = (float*)(smem + 36672);  // [120]
  float* c01L = (float*)(smem + 37152);  // [240][2]
  const int tid = threadIdx.x;
  const int wave = tid >> 6, lane = tid & 63;
  const int m = lane & 15, quad = lane >> 4;
  const int row0 = blockIdx.x * 32;
  const int seq0 = (row0 / LSEQ) * LSEQ;
  // phase 0: consts + stage raw X and X^2 (bf16); rows 0..47, valid r<35
  for (int i = tid; i < 480; i += 256){ cwL[i] = cw[i]; Wd5[(i/4)*5 + (i%4)] = dtw[i]; c01L[i] = c01[i]; }
  for (int i = tid; i < 120; i += 256){ cbL[i] = cb[i]; bdL[i] = dtb[i]; }
  for (int i = tid; i < 48*60; i += 256){
    int r = i/60, c = i%60;
    int grow = row0 - 3 + r;
    bool valid = (r < 35) && (grow >= seq0);
    float v = 0.f;
    if (valid) v = srcb ? b2f(srcb[(size_t)grow*60 + c]) : srcf[(size_t)grow*60 + c];
    XB[r*72 + c]  = f2b(v);
    XSQ[r*72 + c] = f2b(v*v);
  }
  for (int i = tid; i < 48*12; i += 256){
    int r = i/12, c = 60 + i%12;
    XB[r*72 + c] = 0; XSQ[r*72 + c] = 0;
  }
  __syncthreads();
  // phase 1a: row stats via MFMA against ones-column B (3 m-tiles)
  {
    bhalf8 bones;
    #pragma unroll
    for (int j = 0; j < 8; j++) bones[j] = (m == 0) ? (short)0x3F80 : (short)0;
    for (int t = wave; t < 3; t += 4){
      f32x4 as = {0.f,0.f,0.f,0.f}, aq = {0.f,0.f,0.f,0.f};
      #pragma unroll
      for (int ks = 0; ks < 2; ks++){
        bhalf8 ax = *(const bhalf8*)&XB[(t*16 + m)*72 + ks*32 + quad*8];
        bhalf8 a2 = *(const bhalf8*)&XSQ[(t*16 + m)*72 + ks*32 + quad*8];
        as = __builtin_amdgcn_mfma_f32_16x16x32_bf16(ax, bones, as, 0, 0, 0);
        aq = __builtin_amdgcn_mfma_f32_16x16x32_bf16(a2, bones, aq, 0, 0, 0);
      }
      if (m == 0){
        #pragma unroll
        for (int reg = 0; reg < 4; reg++){
          int r = t*16 + quad*4 + reg;
          stats[r*2 + 0] = as[reg];
          stats[r*2 + 1] = aq[reg];
        }
      }
    }
  }
  __syncthreads();
  // phase 1b: sums -> mu, rs
  if (tid < 48){
    float Sx = stats[tid*2], Sq = stats[tid*2+1];
    float mu = Sx * (1.0f/60.0f);
    float var = fmaxf(Sq * (1.0f/60.0f) - mu*mu, 0.f);
    stats[tid*2] = mu;
    stats[tid*2+1] = rsqrtf(var + 1e-5f);
  }
  __syncthreads();
  // phase 2: in_proj MFMA (3 mtiles x 15 ntiles) + LN fixup; zs direct to global
  for (int t = wave; t < 45; t += 4){
    int mtile = t / 15, ntile = t % 15;
    f32x4 acc = {0.f,0.f,0.f,0.f};
    #pragma unroll
    for (int ks = 0; ks < 2; ks++){
      bhalf8 a = *(const bhalf8*)&XB[(mtile*16 + m)*72 + ks*32 + quad*8];
      bhalf8 b = *(const bhalf8*)&ipB[(ntile*16 + m)*64 + ks*32 + quad*8];
      acc = __builtin_amdgcn_mfma_f32_16x16x32_bf16(a, b, acc, 0, 0, 0);
    }
    int n = ntile*16 + m;
    float c1v = c01L[n*2], c0v = c01L[n*2+1];
    #pragma unroll
    for (int reg = 0; reg < 4; reg++){
      int r = mtile*16 + quad*4 + reg;
      int grow = row0 - 3 + r;
      bool valid = (r < 35) && (grow >= seq0);
      float mu = stats[r*2], rs = stats[r*2+1];
      float val = rs*(acc[reg] - mu*c1v) + c0v;
      if (!valid) val = 0.f;
      if (n < 120){
        xinB[r*136 + n] = f2b(val);
      } else if (r >= 3 && r < 35){
        zs[(size_t)(row0 - 3 + r)*120 + (n - 120)] = f2b(siluf_(val));
      }
    }
  }
  __syncthreads();
  // phase 3: conv1d(4 taps)+silu -> xcB bf16 (K-pad 120..127 = 0)
  #pragma unroll
  for (int j = 0; j < 15; j++){
    int i = tid + j*256;
    int r = i/120, c = i%120;
    float a = cbL[c];
    #pragma unroll
    for (int k = 0; k < 4; k++)
      a += cwL[c*4+k] * b2f(xinB[(r+k)*136 + c]);
    a = siluf_(a);
    xcB[r*136 + c] = f2b(a);
  }
  for (int i = tid; i < 32*8; i += 256)
    xcB[(i >> 3)*136 + 120 + (i & 7)] = 0;
  __syncthreads();
  // phase 4: x_proj MFMA: 2 mtiles x 3 ntiles = 6 tiles over 4 waves; K=128
  for (int t = wave; t < 6; t += 4){
    int mtile = t / 3, ntile = t % 3;
    f32x4 acc = {0.f,0.f,0.f,0.f};
    #pragma unroll
    for (int ks = 0; ks < 4; ks++){
      bhalf8 a = *(const bhalf8*)&xcB[(mtile*16 + m)*136 + ks*32 + quad*8];
      bhalf8 b = *(const bhalf8*)&xpB[(ntile*16 + m)*128 + ks*32 + quad*8];
      acc = __builtin_amdgcn_mfma_f32_16x16x32_bf16(a, b, acc, 0, 0, 0);
    }
    int n = ntile*16 + m;
    #pragma unroll
    for (int reg = 0; reg < 4; reg++){
      int r = mtile*16 + quad*4 + reg;
      float val = acc[reg];
      if (n < 4)        dtsh[r*4 + n] = val;
      else if (n < 36){
        BCL[r*32 + (n - 4)] = f2b(val);
        if (n < 20) BLf[r*16 + (n - 4)] = val;
      }
    }
  }
  __syncthreads();
  // ---- no more barriers below ----
  // phase 5: dt_proj + softplus -> delta global (bf16, coalesced)
  #pragma unroll
  for (int j = 0; j < 15; j++){
    int i = tid + j*256;
    int row = i/120, d = i%120;
    float t0 = dtsh[row*4], t1 = dtsh[row*4+1], t2 = dtsh[row*4+2], t3 = dtsh[row*4+3];
    float a = bdL[d] + t0*Wd5[d*5] + t1*Wd5[d*5+1] + t2*Wd5[d*5+2] + t3*Wd5[d*5+3];
    delta[(size_t)(row0 + row)*120 + d] = f2b(softplusf_(a));
  }
  // phase 6: fused scan pass 1 over this block's single 32-row chunk
  if (tid < 120){
    const int d = tid;
    const int b = row0 / LSEQ;
    const int cglob = (row0 % LSEQ) >> 5;
    float A2[16], h[16];
    #pragma unroll
    for (int n = 0; n < 16; n++){ A2[n] = -__expf(A_log[d*16+n]) * 1.44269504f; h[n] = 0.f; }
    bool fastp = true;
    #pragma unroll
    for (int n = 1; n < 16; n++)
      fastp = fastp && (fabsf(A2[n] - (n+1)*A2[0]) <= 1e-4f*fabsf(A2[n]));
    const float w0 = Wd5[d*5], w1 = Wd5[d*5+1], w2 = Wd5[d*5+2], w3 = Wd5[d*5+3];
    const float bd = bdL[d];
    int base = (cglob*BATCH + b)*(DI*16) + d*16;
    if (fastp){
      float P = 1.f;
      const float A20 = A2[0];
      for (int t = 0; t < 32; t++){
        float4 t4 = *(const float4*)&dtsh[t*4];
        float del = softplusf_(bd + t4.x*w0 + t4.y*w1 + t4.z*w2 + t4.w*w3);
        float xcv = b2f(xcB[t*136 + d]);
        float dx = del * xcv;
        float r = exp2f(del * A20);
        P *= r;
        float dA[16]; powers16(r, dA);
        float4 b0 = *(const float4*)&BLf[t*16+0];
        float4 b1 = *(const float4*)&BLf[t*16+4];
        float4 b2 = *(const float4*)&BLf[t*16+8];
        float4 b3 = *(const float4*)&BLf[t*16+12];
        h[0]=dA[0]*h[0]+dx*b0.x;  h[1]=dA[1]*h[1]+dx*b0.y;  h[2]=dA[2]*h[2]+dx*b0.z;  h[3]=dA[3]*h[3]+dx*b0.w;
        h[4]=dA[4]*h[4]+dx*b1.x;  h[5]=dA[5]*h[5]+dx*b1.y;  h[6]=dA[6]*h[6]+dx*b1.z;  h[7]=dA[7]*h[7]+dx*b1.w;
        h[8]=dA[8]*h[8]+dx*b2.x;  h[9]=dA[9]*h[9]+dx*b2.y;  h[10]=dA[10]*h[10]+dx*b2.z; h[11]=dA[11]*h[11]+dx*b2.w;
        h[12]=dA[12]*h[12]+dx*b3.x; h[13]=dA[13]*h[13]+dx*b3.y; h[14]=dA[14]*h[14]+dx*b3.z; h[15]=dA[15]*h[15]+dx*b3.w;
      }
      float apv[16]; powers16(P, apv);
      #pragma unroll
      for (int q = 0; q < 4; q++){
        *(float4*)&ap[base + q*4] = *(float4*)&apv[q*4];
        *(float4*)&he[base + q*4] = *(float4*)&h[q*4];
      }
    } else {
      float apv[16];
      #pragma unroll
      for (int n = 0; n < 16; n++) apv[n] = 1.f;
      for (int t = 0; t < 32; t++){
        float4 t4 = *(const float4*)&dtsh[t*4];
        float del = softplusf_(bd + t4.x*w0 + t4.y*w1 + t4.z*w2 + t4.w*w3);
        float xcv = b2f(xcB[t*136 + d]);
        float dx = del * xcv;
        #pragma unroll
        for (int n = 0; n < 16; n++){
          float dA = exp2f(del * A2[n]);
          apv[n] *= dA;
          h[n] = dA*h[n] + dx*BLf[t*16+n];
        }
      }
      #pragma unroll
      for (int q = 0; q < 4; q++){
        *(float4*)&ap[base + q*4] = *(float4*)&apv[q*4];
        *(float4*)&he[base + q*4] = *(float4*)&h[q*4];
      }
    }
  }
  // final dump: xc, BC -> global, coalesced short4
  for (int i = tid; i < 960; i += 256){
    int r = i/30, off = (i%30)*4;
    *(short4v*)&xcg[(size_t)(row0 + r)*120 + off] = *(const short4v*)&xcB[r*136 + off];
  }
  for (int i = tid; i < 256; i += 256)
    *(short4v*)&BCg[(size_t)row0*32 + i*4] = *(const short4v*)&BCL[i*4];
}

// =============== scan pass 2: hierarchical block-parallel chunk scan ===============
__global__ __launch_bounds__(256) void k_scan2(float* __restrict__ ap, const float* __restrict__ he)
{
  __shared__ float aggA[16*17];
  __shared__ float aggB[16*17];
  const int tid = threadIdx.x;
  const int n = tid & 15, j = tid >> 4;
  const int sbase = blockIdx.x*16 + n;
  const int stride = BATCH*DI*16;
  {
    float A = 1.f, B = 0.f;
    int idx = (j*32)*stride + sbase;
    #pragma unroll 4
    for (int k = 0; k < 32; k++){
      float a = ap[idx], h = he[idx];
      B = a*B + h;
      A *= a;
      idx += stride;
    }
    aggA[n*17 + j] = A;
    aggB[n*17 + j] = B;
  }
  __syncthreads();
  if (tid < 16){
    float B = 0.f;
    #pragma unroll
    for (int jj = 0; jj < 16; jj++){
      float Af = aggA[tid*17 + jj];
      float Bf = aggB[tid*17 + jj];
      aggB[tid*17 + jj] = B;
      B = Af*B + Bf;
    }
  }
  __syncthreads();
  {
    float H = aggB[n*17 + j];
    int idx = (j*32)*stride + sbase;
    #pragma unroll 4
    for (int k = 0; k < 32; k++){
      float a = ap[idx], h = he[idx];
      ap[idx] = H;
      H = a*H + h;
      idx += stride;
    }
  }
}

// =============== scan pass 3 + out_proj fused (bf16 in, bf16 hout) ===============
__global__ __launch_bounds__(128) void k_scan3o(
    const short* __restrict__ delta, const short* __restrict__ xc,
    const short* __restrict__ BCg, const short* __restrict__ zs,
    const float* __restrict__ h0, const float* __restrict__ A_log,
    const float* __restrict__ Dsk, const float* __restrict__ opw,
    short* __restrict__ hout)
{
  __shared__ float BCl[TCH*32];
  __shared__ float yL[TCH*124];
  const int tid = threadIdx.x;
  const int c = blockIdx.x % NCH, b = blockIdx.x / NCH;
  const size_t rowbase = (size_t)b*LSEQ + (size_t)c*TCH;
  for (int i = tid; i < TCH*32; i += 128)
    BCl[i] = b2f(BCg[rowbase*32 + i]);
  __syncthreads();
  const int d = tid;
  if (d < DI){
    float A2[16], h[16];
    int base = (c*BATCH + b)*(DI*16) + d*16;
    #pragma unroll
    for (int n = 0; n < 16; n++){
      A2[n] = -__expf(A_log[d*16+n]) * 1.44269504f;
      h[n] = h0[base+n];
    }
    bool fastp = true;
    #pragma unroll
    for (int n = 1; n < 16; n++)
      fastp = fastp && (fabsf(A2[n] - (n+1)*A2[0]) <= 1e-4f*fabsf(A2[n]));
    float Dv = Dsk[d];
    if (fastp){
      const float A20 = A2[0];
      for (int t = 0; t < TCH; t++){
        float del = b2f(delta[(rowbase+t)*DI + d]);
        float xcv = b2f(xc[(rowbase+t)*DI + d]);
        float zv  = b2f(zs[(rowbase+t)*DI + d]);
        float dx = del * xcv;
        float r = exp2f(del * A20);
        float dA[16]; powers16(r, dA);
        float4 b0 = *(const float4*)&BCl[t*32+0];
        float4 b1 = *(const float4*)&BCl[t*32+4];
        float4 b2 = *(const float4*)&BCl[t*32+8];
        float4 b3 = *(const float4*)&BCl[t*32+12];
        float4 c0 = *(const float4*)&BCl[t*32+16];
        float4 c1 = *(const float4*)&BCl[t*32+20];
        float4 c2 = *(const float4*)&BCl[t*32+24];
        float4 c3 = *(const float4*)&BCl[t*32+28];
        h[0]=dA[0]*h[0]+dx*b0.x;  h[1]=dA[1]*h[1]+dx*b0.y;  h[2]=dA[2]*h[2]+dx*b0.z;  h[3]=dA[3]*h[3]+dx*b0.w;
        h[4]=dA[4]*h[4]+dx*b1.x;  h[5]=dA[5]*h[5]+dx*b1.y;  h[6]=dA[6]*h[6]+dx*b1.z;  h[7]=dA[7]*h[7]+dx*b1.w;
        h[8]=dA[8]*h[8]+dx*b2.x;  h[9]=dA[9]*h[9]+dx*b2.y;  h[10]=dA[10]*h[10]+dx*b2.z; h[11]=dA[11]*h[11]+dx*b2.w;
        h[12]=dA[12]*h[12]+dx*b3.x; h[13]=dA[13]*h[13]+dx*b3.y; h[14]=dA[14]*h[14]+dx*b3.z; h[15]=dA[15]*h[15]+dx*b3.w;
        float acc = h[0]*c0.x + h[1]*c0.y + h[2]*c0.z + h[3]*c0.w
                  + h[4]*c1.x + h[5]*c1.y + h[6]*c1.z + h[7]*c1.w
                  + h[8]*c2.x + h[9]*c2.y + h[10]*c2.z + h[11]*c2.w
                  + h[12]*c3.x + h[13]*c3.y + h[14]*c3.z + h[15]*c3.w;
        yL[t*124 + d] = (acc + Dv*xcv) * zv;
      }
    } else {
      for (int t = 0; t < TCH; t++){
        float del = b2f(delta[(rowbase+t)*DI + d]);
        float xcv = b2f(xc[(rowbase+t)*DI + d]);
        float zv  = b2f(zs[(rowbase+t)*DI + d]);
        float dx = del * xcv;
        float acc = 0.f;
        #pragma unroll
        for (int n = 0; n < 16; n++){
          float dA = exp2f(del * A2[n]);
          h[n] = dA*h[n] + dx*BCl[t*32+n];
          acc += h[n]*BCl[t*32+16+n];
        }
        yL[t*124 + d] = (acc + Dv*xcv) * zv;
      }
    }
  }
  __syncthreads();
  if (tid < 120){
    const int cg = tid % 15, rg = tid / 15;
    float acc[4][4];
    #pragma unroll
    for (int r = 0; r < 4; r++){ acc[r][0]=0.f; acc[r][1]=0.f; acc[r][2]=0.f; acc[r][3]=0.f; }
    for (int kg = 0; kg < 30; kg++){
      int k = kg*4;
      float4 b0 = *(const float4*)&opw[(size_t)(cg*4+0)*120 + k];
      float4 b1 = *(const float4*)&opw[(size_t)(cg*4+1)*120 + k];
      float4 b2 = *(const float4*)&opw[(size_t)(cg*4+2)*120 + k];
      float4 b3 = *(const float4*)&opw[(size_t)(cg*4+3)*120 + k];
      #pragma unroll
      for (int r = 0; r < 4; r++){
        float4 a = *(const float4*)&yL[(rg*4+r)*124 + k];
        acc[r][0] += a.x*b0.x + a.y*b0.y + a.z*b0.z + a.w*b0.w;
        acc[r][1] += a.x*b1.x + a.y*b1.y + a.z*b1.z + a.w*b1.w;
        acc[r][2] += a.x*b2.x + a.y*b2.y + a.z*b2.z + a.w*b2.w;
        acc[r][3] += a.x*b3.x + a.y*b3.y + a.z*b3.z + a.w*b3.w;
      }
    }
    #pragma unroll
    for (int r = 0; r < 4; r++){
      short4v v;
      v.x = f2b(acc[r][0]); v.y = f2b(acc[r][1]); v.z = f2b(acc[r][2]); v.w = f2b(acc[r][3]);
      *(short4v*)&hout[(rowbase + rg*4 + r)*60 + cg*4] = v;
    }
  }
}

// =============== conv2d weight pack: w[co][ci][3][3] -> bf16 wB[tap][co64][ci64] ===============
__global__ __launch_bounds__(256) void k_wB(const float* __restrict__ w, short* __restrict__ wB)
{
  int i = blockIdx.x*256 + threadIdx.x;
  if (i >= 9*64*64) return;
  int ci = i & 63, co = (i >> 6) & 63, tap = i >> 12;
  float v = 0.f;
  if (co < 60 && ci < 60) v = w[((size_t)co*60 + ci)*9 + tap];
  wB[i] = f2b(v);
}

// =============== 3x3 SAME conv2d via bf16 MFMA + bias + residual ===============
__global__ __launch_bounds__(256) void k_conv2d(
    const short* __restrict__ hin, const short* __restrict__ wB,
    const float* __restrict__ cb, const float* __restrict__ xres,
    float* __restrict__ out)
{
  __shared__ short tile[3*66*72];
  const int tid = threadIdx.x;
  const int blk = blockIdx.x;
  const int xhalf = blk & 1;
  const int yy = (blk >> 1) & 127;
  const int b = blk >> 8;
  const int x0 = xhalf*64;
  for (int i = tid; i < 3*66*72; i += 256){
    int ci = i % 72;
    int xx = (i / 72) % 66;
    int row = i / (72*66);
    int gy = yy - 1 + row, gx = x0 - 1 + xx;
    short v = 0;
    if (ci < 60 && gy >= 0 && gy < HH && gx >= 0 && gx < WW)
      v = hin[((size_t)b*LSEQ + gy*WW + gx)*60 + ci];
    tile[i] = v;
  }
  __syncthreads();
  const int wave = tid >> 6, lane = tid & 63;
  const int m = lane & 15, quad = lane >> 4;
  f32x4 acc0 = {0.f,0.f,0.f,0.f}, acc1 = {0.f,0.f,0.f,0.f};
  f32x4 acc2 = {0.f,0.f,0.f,0.f}, acc3 = {0.f,0.f,0.f,0.f};
  #pragma unroll
  for (int tap = 0; tap < 9; tap++){
    const int ky = tap/3, kx = tap%3;
    const short* arow = &tile[(ky*66 + wave*16 + m + kx)*72];
    const short* brow = wB + tap*4096;
    #pragma unroll
    for (int kh = 0; kh < 2; kh++){
      const int k0 = kh*32 + quad*8;
      bhalf8 a = *(const bhalf8*)(arow + k0);
      bhalf8 b0 = *(const bhalf8*)(brow + (0*16 + m)*64 + k0);
      bhalf8 b1 = *(const bhalf8*)(brow + (1*16 + m)*64 + k0);
      bhalf8 b2 = *(const bhalf8*)(brow + (2*16 + m)*64 + k0);
      bhalf8 b3 = *(const bhalf8*)(brow + (3*16 + m)*64 + k0);
      acc0 = __builtin_amdgcn_mfma_f32_16x16x32_bf16(a, b0, acc0, 0, 0, 0);
      acc1 = __builtin_amdgcn_mfma_f32_16x16x32_bf16(a, b1, acc1, 0, 0, 0);
      acc2 = __builtin_amdgcn_mfma_f32_16x16x32_bf16(a, b2, acc2, 0, 0, 0);
      acc3 = __builtin_amdgcn_mfma_f32_16x16x32_bf16(a, b3, acc3, 0, 0, 0);
    }
  }
  const size_t rowb = (size_t)b*LSEQ + yy*WW + x0;
  f32x4 accs[4] = {acc0, acc1, acc2, acc3};
  #pragma unroll
  for (int nt = 0; nt < 4; nt++){
    int co = nt*16 + m;
    if (co < 60){
      float bias = cb[co];
      #pragma unroll
      for (int reg = 0; reg < 4; reg++){
        int px = wave*16 + quad*4 + reg;
        size_t o = (rowb + px)*60 + co;
        out[o] = accs[nt][reg] + bias + xres[o];
      }
    }
  }
}

extern "C" void kernel_launch(void* const* d_in, const int* in_sizes, int n_in,
                              void* d_out, int out_size, void* d_ws, size_t ws_size,
                              hipStream_t stream)
{
  const float* x      = (const float*)d_in[0];
  const float* ln_w   = (const float*)d_in[1];
  const float* ln_b   = (const float*)d_in[2];
  const float* ipw    = (const float*)d_in[3];
  const float* cw     = (const float*)d_in[4];
  const float* cb1    = (const float*)d_in[5];
  const float* xpw    = (const float*)d_in[6];
  const float* dtw    = (const float*)d_in[7];
  const float* dtb    = (const float*)d_in[8];
  const float* A_log  = (const float*)d_in[9];
  const float* Dsk    = (const float*)d_in[10];
  const float* opw    = (const float*)d_in[11];
  const float* c2w    = (const float*)d_in[12];
  const float* c2b    = (const float*)d_in[13];
  float* out = (float*)d_out;

  char* ws = (char*)d_ws;
  size_t off = 0;
  short* zsb   = (short*)(ws + off); off += (size_t)BATCH*LSEQ*DI*2;
  short* xcb   = (short*)(ws + off); off += (size_t)BATCH*LSEQ*DI*2;
  short* dlt   = (short*)(ws + off); off += (size_t)BATCH*LSEQ*DI*2;
  short* BCg   = (short*)(ws + off); off += (size_t)BATCH*LSEQ*32*2;
  float* apb   = (float*)(ws + off); off += (size_t)NCH*BATCH*DI*16*4;
  float* heb   = (float*)(ws + off); off += (size_t)NCH*BATCH*DI*16*4;
  short* hcur  = (short*)(ws + off); off += (size_t)BATCH*LSEQ*DM*2;
  short* wBb   = (short*)(ws + off); off += (size_t)9*64*64*2;
  short* pkb   = (short*)(ws + off); off += (size_t)(2*240*64 + 2*48*128)*2;
  float* c01b  = (float*)(ws + off); off += (size_t)2*240*2*4;

  const int rows = BATCH*LSEQ;
  k_pack<<<(43008 + 480 + 255)/256, 256, 0, stream>>>(ipw, xpw, ln_w, ln_b, pkb, c01b);
  for (int layer = 0; layer < 2; layer++){
    const float* srcf = (layer == 0) ? x : nullptr;
    const short* srcb = (layer == 0) ? nullptr : hcur;
    k_lnxp<<<rows/32, 256, 0, stream>>>(srcf, srcb,
                                        pkb + (size_t)layer*240*64,
                                        c01b + (size_t)layer*240*2,
                                        cw + layer*DI*4, cb1 + layer*DI,
                                        pkb + 30720 + (size_t)layer*48*128,
                                        dtw + (size_t)layer*DI*4, dtb + layer*DI,
                                        A_log + (size_t)layer*DI*16,
                                        zsb, xcb, dlt, BCg, apb, heb);
    k_scan2<<<BATCH*DI, 256, 0, stream>>>(apb, heb);
    k_scan3o<<<BATCH*NCH, 128, 0, stream>>>(dlt, xcb, BCg, zsb, apb, A_log + (size_t)layer*DI*16,
                                            Dsk + layer*DI, opw + (size_t)layer*DM*DI, hcur);
  }
  k_wB<<<(9*64*64+255)/256, 256, 0, stream>>>(c2w, wBb);
  k_conv2d<<<BATCH*HH*2, 256, 0, stream>>>(hcur, wBb, c2b, x, out);
}